// Round 1
// baseline (955.046 us; speedup 1.0000x reference)
//
#include <hip/hip_runtime.h>

// ---------- types ----------
typedef short short8 __attribute__((ext_vector_type(8)));
typedef unsigned short ushort8 __attribute__((ext_vector_type(8)));
typedef float float4v __attribute__((ext_vector_type(4)));

// ---------- bf16 helpers (bit-level, no header dependence) ----------
__device__ __forceinline__ unsigned short f2bf(float f) {
    union { float f; unsigned u; } v; v.f = f;
    unsigned r = v.u + 0x7fffu + ((v.u >> 16) & 1u);   // RNE
    return (unsigned short)(r >> 16);
}
__device__ __forceinline__ float bf2f(unsigned short s) {
    union { unsigned u; float f; } v; v.u = ((unsigned)s) << 16;
    return v.f;
}

// ---------- async global->LDS, 16B per lane ----------
__device__ __forceinline__ void async_copy16(const void* g, void* l) {
    __builtin_amdgcn_global_load_lds(
        (__attribute__((address_space(1))) void*)g,
        (__attribute__((address_space(3))) void*)l,
        16, 0, 0);
}

// ---------- fp32 -> bf16 cast (vectorized) ----------
__global__ __launch_bounds__(256) void cast_bf16_kernel(
        const float* __restrict__ in, unsigned short* __restrict__ out, int n) {
    int i4 = (blockIdx.x * 256 + threadIdx.x) * 4;
    if (i4 < n) {
        float4 f = *(const float4*)(in + i4);
        ushort4 u;
        u.x = f2bf(f.x); u.y = f2bf(f.y); u.z = f2bf(f.z); u.w = f2bf(f.w);
        *(ushort4*)(out + i4) = u;
    }
}

// ---------- bf16 GEMM, C[m,n] = sum_k A[m,k]*B[n,k]  (both row-major [rows,K]) ----------
// 128x128 tile, 256 threads = 4 waves (2x2), each wave 64x64 via 4x4 MFMA 16x16x32.
// EPI: 0 = fp32 out, 1 = bf16 out, 2 = fp32 out + bias[col] + resid[row*N+col]
template<int EPI>
__global__ __launch_bounds__(256) void gemm_bt_kernel(
        const unsigned short* __restrict__ A,
        const unsigned short* __restrict__ B,
        float* __restrict__ Cf,
        unsigned short* __restrict__ Cb,
        const float* __restrict__ bias,
        const float* __restrict__ resid,
        int Mclamp, int N, int K) {
    __shared__ unsigned short As[128 * 32];   // 8 KB, [row][k] row-major
    __shared__ unsigned short Bs[128 * 32];   // 8 KB

    const int tid  = threadIdx.x;
    const int lane = tid & 63;
    const int wave = tid >> 6;
    const int wm   = (wave >> 1) * 64;
    const int wn   = (wave & 1) * 64;
    const int lr   = lane & 15;   // fragment row / C col
    const int lq   = lane >> 4;   // quad

    const int bm = blockIdx.x * 128;
    const int bn = blockIdx.y * 128;

    float4v acc[4][4] = {};

    // staging: chunk c = r*256 + tid, row = c>>2 (0..127), k8 = (c&3)*8
    const int row_s = tid >> 2;
    const int kk    = (tid & 3) * 8;
    int ar0 = bm + row_s;       if (ar0 >= Mclamp) ar0 = Mclamp - 1;
    int ar1 = bm + row_s + 64;  if (ar1 >= Mclamp) ar1 = Mclamp - 1;
    const int br0 = bn + row_s;
    const int br1 = bn + row_s + 64;

    const unsigned short* a0 = A + (size_t)ar0 * K + kk;
    const unsigned short* a1 = A + (size_t)ar1 * K + kk;
    const unsigned short* b0 = B + (size_t)br0 * K + kk;
    const unsigned short* b1 = B + (size_t)br1 * K + kk;

    char* AsD0 = (char*)As + (size_t)tid * 16;
    char* AsD1 = (char*)As + (size_t)(256 + tid) * 16;
    char* BsD0 = (char*)Bs + (size_t)tid * 16;
    char* BsD1 = (char*)Bs + (size_t)(256 + tid) * 16;

    for (int ks = 0; ks < K; ks += 32) {
        async_copy16(a0 + ks, AsD0);
        async_copy16(a1 + ks, AsD1);
        async_copy16(b0 + ks, BsD0);
        async_copy16(b1 + ks, BsD1);
        __syncthreads();   // compiler drains vmcnt before barrier

        short8 af[4], bfr[4];
        #pragma unroll
        for (int i = 0; i < 4; ++i)
            af[i] = *(const short8*)(As + (wm + i * 16 + lr) * 32 + lq * 8);
        #pragma unroll
        for (int j = 0; j < 4; ++j)
            bfr[j] = *(const short8*)(Bs + (wn + j * 16 + lr) * 32 + lq * 8);

        #pragma unroll
        for (int i = 0; i < 4; ++i)
            #pragma unroll
            for (int j = 0; j < 4; ++j)
                acc[i][j] = __builtin_amdgcn_mfma_f32_16x16x32_bf16(
                                af[i], bfr[j], acc[i][j], 0, 0, 0);
        __syncthreads();   // protect LDS before next stage
    }

    // epilogue: C/D layout col=lane&15, row=(lane>>4)*4+reg   [m89-verified]
    #pragma unroll
    for (int i = 0; i < 4; ++i) {
        #pragma unroll
        for (int r = 0; r < 4; ++r) {
            const int row = bm + wm + i * 16 + lq * 4 + r;
            const size_t base = (size_t)row * N;
            #pragma unroll
            for (int j = 0; j < 4; ++j) {
                const int col = bn + wn + j * 16 + lr;
                const float v = acc[i][j][r];
                const size_t idx = base + col;
                if (EPI == 2)      Cf[idx] = v + bias[col] + resid[idx];
                else if (EPI == 1) Cb[idx] = f2bf(v);
                else               Cf[idx] = v;
            }
        }
    }
}

// ---------- fused dual attention (cross T=77 + id L=32), 1 thread = 1 query row ----------
// Q bf16 [B*S,1280]; Kp/Vp fp32 [384,1280] rows=(b*77+t); IKp/IVp fp32 [128,1280] rows=(b*32+t)
// writes combined bf16 [B*S,1280] at col h*64+d
__global__ __launch_bounds__(256) void attn_kernel(
        const unsigned short* __restrict__ Q,
        const float* __restrict__ Kp, const float* __restrict__ Vp,
        const float* __restrict__ IKp, const float* __restrict__ IVp,
        unsigned short* __restrict__ Cmb) {
    const int b = blockIdx.z;
    const int h = blockIdx.y;
    const int s = blockIdx.x * 256 + threadIdx.x;
    const int hoff = h * 64;

    __shared__ float Kl[77 * 64];
    __shared__ float Vl[77 * 64];
    __shared__ float IKl[32 * 64];
    __shared__ float IVl[32 * 64];

    // stage K/V (float4 loads; 77*16 = 1232 float4 each)
    for (int i = threadIdx.x; i < 77 * 16; i += 256) {
        const int t = i >> 4, c4 = i & 15;
        const size_t src = (size_t)(b * 77 + t) * 1280 + hoff + c4 * 4;
        ((float4*)Kl)[i] = *(const float4*)(Kp + src);
        ((float4*)Vl)[i] = *(const float4*)(Vp + src);
    }
    for (int i = threadIdx.x; i < 32 * 16; i += 256) {
        const int t = i >> 4, c4 = i & 15;
        const size_t src = (size_t)(b * 32 + t) * 1280 + hoff + c4 * 4;
        ((float4*)IKl)[i] = *(const float4*)(IKp + src);
        ((float4*)IVl)[i] = *(const float4*)(IVp + src);
    }
    __syncthreads();

    // load q row (bf16 -> fp32)
    float q[64];
    const unsigned short* qp = Q + (size_t)(b * 4096 + s) * 1280 + hoff;
    #pragma unroll
    for (int c = 0; c < 8; ++c) {
        short8 v = *(const short8*)(qp + c * 8);
        #pragma unroll
        for (int j = 0; j < 8; ++j) q[c * 8 + j] = bf2f((unsigned short)v[j]);
    }

    const float scale = 0.125f;   // 1/sqrt(64)

    // cross attention (no max-subtraction: |scores*scale| << 88)
    float accC[64];
    #pragma unroll
    for (int d = 0; d < 64; ++d) accC[d] = 0.f;
    float lC = 0.f;
    #pragma unroll 1
    for (int j = 0; j < 77; ++j) {
        const float* kr = Kl + j * 64;
        float s0 = 0.f, s1 = 0.f, s2 = 0.f, s3 = 0.f;
        #pragma unroll
        for (int d = 0; d < 64; d += 4) {
            s0 += q[d + 0] * kr[d + 0];
            s1 += q[d + 1] * kr[d + 1];
            s2 += q[d + 2] * kr[d + 2];
            s3 += q[d + 3] * kr[d + 3];
        }
        const float p = __expf(((s0 + s1) + (s2 + s3)) * scale);
        lC += p;
        const float* vr = Vl + j * 64;
        #pragma unroll
        for (int d = 0; d < 64; ++d) accC[d] += p * vr[d];
    }

    // id attention
    float accI[64];
    #pragma unroll
    for (int d = 0; d < 64; ++d) accI[d] = 0.f;
    float lI = 0.f;
    #pragma unroll 1
    for (int j = 0; j < 32; ++j) {
        const float* kr = IKl + j * 64;
        float s0 = 0.f, s1 = 0.f, s2 = 0.f, s3 = 0.f;
        #pragma unroll
        for (int d = 0; d < 64; d += 4) {
            s0 += q[d + 0] * kr[d + 0];
            s1 += q[d + 1] * kr[d + 1];
            s2 += q[d + 2] * kr[d + 2];
            s3 += q[d + 3] * kr[d + 3];
        }
        const float p = __expf(((s0 + s1) + (s2 + s3)) * scale);
        lI += p;
        const float* vr = IVl + j * 64;
        #pragma unroll
        for (int d = 0; d < 64; ++d) accI[d] += p * vr[d];
    }

    const float rC = 1.f / lC;
    const float rI = 1.f / lI;

    unsigned short* op = Cmb + (size_t)(b * 4096 + s) * 1280 + hoff;
    #pragma unroll
    for (int c = 0; c < 8; ++c) {
        ushort8 u;
        #pragma unroll
        for (int j = 0; j < 8; ++j) {
            const int d = c * 8 + j;
            u[j] = f2bf(accC[d] * rC + accI[d] * rI);
        }
        *(ushort8*)(op + c * 8) = u;
    }
}

// ---------- host launch ----------
extern "C" void kernel_launch(void* const* d_in, const int* in_sizes, int n_in,
                              void* d_out, int out_size, void* d_ws, size_t ws_size,
                              hipStream_t stream) {
    const float* hs  = (const float*)d_in[0];   // [4,4096,1280]
    const float* enc = (const float*)d_in[1];   // [4,77,2048]
    const float* idm = (const float*)d_in[2];   // [4,32,2048]
    const float* Wq  = (const float*)d_in[3];   // [1280,1280]
    const float* Wk  = (const float*)d_in[4];   // [1280,2048]
    const float* Wv  = (const float*)d_in[5];
    const float* Wik = (const float*)d_in[6];
    const float* Wiv = (const float*)d_in[7];
    const float* Wo  = (const float*)d_in[8];   // [1280,1280]
    const float* bo  = (const float*)d_in[9];   // [1280]
    float* out = (float*)d_out;

    char* ws = (char*)d_ws;
    size_t off = 0;
    auto carve = [&](size_t bytes) {
        char* p = ws + off;
        off += (bytes + 255) & ~(size_t)255;
        return p;
    };

    unsigned short* Xh   = (unsigned short*)carve(16384ULL * 1280 * 2); // also 'combined'
    unsigned short* Wq_b = (unsigned short*)carve(1280ULL * 1280 * 2);
    unsigned short* Wk_b = (unsigned short*)carve(1280ULL * 2048 * 2);
    unsigned short* Wv_b = (unsigned short*)carve(1280ULL * 2048 * 2);
    unsigned short* Wik_b= (unsigned short*)carve(1280ULL * 2048 * 2);
    unsigned short* Wiv_b= (unsigned short*)carve(1280ULL * 2048 * 2);
    unsigned short* Wo_b = (unsigned short*)carve(1280ULL * 1280 * 2);
    unsigned short* Encb = (unsigned short*)carve(308ULL * 2048 * 2);
    unsigned short* Idb  = (unsigned short*)carve(128ULL * 2048 * 2);
    unsigned short* Qb   = (unsigned short*)carve(16384ULL * 1280 * 2);
    float* Kp  = (float*)carve(384ULL * 1280 * 4);
    float* Vp  = (float*)carve(384ULL * 1280 * 4);
    float* IKp = (float*)carve(128ULL * 1280 * 4);
    float* IVp = (float*)carve(128ULL * 1280 * 4);
    (void)ws_size; (void)in_sizes; (void)n_in; (void)out_size;

    auto cast = [&](const float* src, unsigned short* dst, int n) {
        cast_bf16_kernel<<<(n / 4 + 255) / 256, 256, 0, stream>>>(src, dst, n);
    };
    cast(hs,  Xh,   4 * 4096 * 1280);
    cast(Wq,  Wq_b, 1280 * 1280);
    cast(Wk,  Wk_b, 1280 * 2048);
    cast(Wv,  Wv_b, 1280 * 2048);
    cast(Wik, Wik_b,1280 * 2048);
    cast(Wiv, Wiv_b,1280 * 2048);
    cast(Wo,  Wo_b, 1280 * 1280);
    cast(enc, Encb, 4 * 77 * 2048);
    cast(idm, Idb,  4 * 32 * 2048);

    // Q = hs @ Wq^T   -> bf16 [16384,1280]
    gemm_bt_kernel<1><<<dim3(128, 10), 256, 0, stream>>>(
        Xh, Wq_b, nullptr, Qb, nullptr, nullptr, 16384, 1280, 1280);
    // K/V projections -> fp32 (padded to 384 rows)
    gemm_bt_kernel<0><<<dim3(3, 10), 256, 0, stream>>>(
        Encb, Wk_b, Kp, nullptr, nullptr, nullptr, 308, 1280, 2048);
    gemm_bt_kernel<0><<<dim3(3, 10), 256, 0, stream>>>(
        Encb, Wv_b, Vp, nullptr, nullptr, nullptr, 308, 1280, 2048);
    gemm_bt_kernel<0><<<dim3(1, 10), 256, 0, stream>>>(
        Idb, Wik_b, IKp, nullptr, nullptr, nullptr, 128, 1280, 2048);
    gemm_bt_kernel<0><<<dim3(1, 10), 256, 0, stream>>>(
        Idb, Wiv_b, IVp, nullptr, nullptr, nullptr, 128, 1280, 2048);

    // fused cross+id attention -> combined (reuses Xh buffer)
    attn_kernel<<<dim3(16, 20, 4), 256, 0, stream>>>(Qb, Kp, Vp, IKp, IVp, Xh);

    // out = combined @ Wo^T + bo + residual(hs)   -> fp32 d_out
    gemm_bt_kernel<2><<<dim3(128, 10), 256, 0, stream>>>(
        Xh, Wo_b, out, nullptr, bo, hs, 16384, 1280, 1280);
}

// Round 2
// 896.888 us; speedup vs baseline: 1.0648x; 1.0648x over previous
//
#include <hip/hip_runtime.h>

// ---------- types ----------
typedef short short8 __attribute__((ext_vector_type(8)));
typedef unsigned short ushort8 __attribute__((ext_vector_type(8)));
typedef float float4v __attribute__((ext_vector_type(4)));

// ---------- bf16 helpers (bit-level, no header dependence) ----------
__device__ __forceinline__ unsigned short f2bf(float f) {
    union { float f; unsigned u; } v; v.f = f;
    unsigned r = v.u + 0x7fffu + ((v.u >> 16) & 1u);   // RNE
    return (unsigned short)(r >> 16);
}
__device__ __forceinline__ float bf2f(unsigned short s) {
    union { unsigned u; float f; } v; v.u = ((unsigned)s) << 16;
    return v.f;
}

// ---------- async global->LDS, 16B per lane ----------
__device__ __forceinline__ void async_copy16(const void* g, void* l) {
    __builtin_amdgcn_global_load_lds(
        (__attribute__((address_space(1))) void*)g,
        (__attribute__((address_space(3))) void*)l,
        16, 0, 0);
}

// ---------- fp32 -> bf16 cast (vectorized) ----------
__global__ __launch_bounds__(256) void cast_bf16_kernel(
        const float* __restrict__ in, unsigned short* __restrict__ out, int n) {
    int i4 = (blockIdx.x * 256 + threadIdx.x) * 4;
    if (i4 < n) {
        float4 f = *(const float4*)(in + i4);
        ushort4 u;
        u.x = f2bf(f.x); u.y = f2bf(f.y); u.z = f2bf(f.z); u.w = f2bf(f.w);
        *(ushort4*)(out + i4) = u;
    }
}

// batched small casts: one launch covers up to 8 tensors (grid.y selects)
struct CastBatch {
    const float* src[8];
    unsigned short* dst[8];
    int n[8];
};
__global__ __launch_bounds__(256) void cast_batch_kernel(CastBatch cb) {
    const int t = blockIdx.y;
    const int n = cb.n[t];
    int i4 = (blockIdx.x * 256 + threadIdx.x) * 4;
    if (i4 < n) {
        float4 f = *(const float4*)(cb.src[t] + i4);
        ushort4 u;
        u.x = f2bf(f.x); u.y = f2bf(f.y); u.z = f2bf(f.z); u.w = f2bf(f.w);
        *(ushort4*)(cb.dst[t] + i4) = u;
    }
}

// ---------- bf16 GEMM core, C[m,n] = sum_k A[m,k]*B[n,k]  (both row-major [rows,K]) ----------
// 128x128 tile, 256 threads = 4 waves (2x2), each wave 64x64 via 4x4 MFMA 16x16x32.
// EPI: 0 = fp32 out, 1 = bf16 out, 2 = fp32 out + bias[col] + resid[row*N+col]
template<int EPI>
__device__ __forceinline__ void gemm_core(
        const unsigned short* __restrict__ A,
        const unsigned short* __restrict__ B,
        float* __restrict__ Cf,
        unsigned short* __restrict__ Cb,
        const float* __restrict__ bias,
        const float* __restrict__ resid,
        int Mclamp, int N, int K, int bm, int bn) {
    __shared__ unsigned short As[128 * 32];   // 8 KB, [row][k] row-major
    __shared__ unsigned short Bs[128 * 32];   // 8 KB

    const int tid  = threadIdx.x;
    const int lane = tid & 63;
    const int wave = tid >> 6;
    const int wm   = (wave >> 1) * 64;
    const int wn   = (wave & 1) * 64;
    const int lr   = lane & 15;   // fragment row / C col
    const int lq   = lane >> 4;   // quad

    float4v acc[4][4] = {};

    const int row_s = tid >> 2;
    const int kk    = (tid & 3) * 8;
    int ar0 = bm + row_s;       if (ar0 >= Mclamp) ar0 = Mclamp - 1;
    int ar1 = bm + row_s + 64;  if (ar1 >= Mclamp) ar1 = Mclamp - 1;
    const int br0 = bn + row_s;
    const int br1 = bn + row_s + 64;

    const unsigned short* a0 = A + (size_t)ar0 * K + kk;
    const unsigned short* a1 = A + (size_t)ar1 * K + kk;
    const unsigned short* b0 = B + (size_t)br0 * K + kk;
    const unsigned short* b1 = B + (size_t)br1 * K + kk;

    char* AsD0 = (char*)As + (size_t)tid * 16;
    char* AsD1 = (char*)As + (size_t)(256 + tid) * 16;
    char* BsD0 = (char*)Bs + (size_t)tid * 16;
    char* BsD1 = (char*)Bs + (size_t)(256 + tid) * 16;

    for (int ks = 0; ks < K; ks += 32) {
        async_copy16(a0 + ks, AsD0);
        async_copy16(a1 + ks, AsD1);
        async_copy16(b0 + ks, BsD0);
        async_copy16(b1 + ks, BsD1);
        __syncthreads();

        short8 af[4], bfr[4];
        #pragma unroll
        for (int i = 0; i < 4; ++i)
            af[i] = *(const short8*)(As + (wm + i * 16 + lr) * 32 + lq * 8);
        #pragma unroll
        for (int j = 0; j < 4; ++j)
            bfr[j] = *(const short8*)(Bs + (wn + j * 16 + lr) * 32 + lq * 8);

        #pragma unroll
        for (int i = 0; i < 4; ++i)
            #pragma unroll
            for (int j = 0; j < 4; ++j)
                acc[i][j] = __builtin_amdgcn_mfma_f32_16x16x32_bf16(
                                af[i], bfr[j], acc[i][j], 0, 0, 0);
        __syncthreads();
    }

    // epilogue: C/D layout col=lane&15, row=(lane>>4)*4+reg   [m89-verified]
    #pragma unroll
    for (int i = 0; i < 4; ++i) {
        #pragma unroll
        for (int r = 0; r < 4; ++r) {
            const int row = bm + wm + i * 16 + lq * 4 + r;
            const size_t base = (size_t)row * N;
            #pragma unroll
            for (int j = 0; j < 4; ++j) {
                const int col = bn + wn + j * 16 + lr;
                const float v = acc[i][j][r];
                const size_t idx = base + col;
                if (EPI == 2)      Cf[idx] = v + bias[col] + resid[idx];
                else if (EPI == 1) Cb[idx] = f2bf(v);
                else               Cf[idx] = v;
            }
        }
    }
}

template<int EPI>
__global__ __launch_bounds__(256) void gemm_bt_kernel(
        const unsigned short* __restrict__ A,
        const unsigned short* __restrict__ B,
        float* __restrict__ Cf,
        unsigned short* __restrict__ Cb,
        const float* __restrict__ bias,
        const float* __restrict__ resid,
        int Mclamp, int N, int K) {
    gemm_core<EPI>(A, B, Cf, Cb, bias, resid, Mclamp, N, K,
                   blockIdx.x * 128, blockIdx.y * 128);
}

// fused K+V projection (shared A); blockIdx.z picks weight/output pair
__global__ __launch_bounds__(256) void gemm_kv_kernel(
        const unsigned short* __restrict__ A,
        const unsigned short* __restrict__ B0,
        const unsigned short* __restrict__ B1,
        float* __restrict__ C0,
        float* __restrict__ C1,
        int Mclamp, int N, int K) {
    const unsigned short* B = blockIdx.z ? B1 : B0;
    float* C = blockIdx.z ? C1 : C0;
    gemm_core<0>(A, B, C, nullptr, nullptr, nullptr, Mclamp, N, K,
                 blockIdx.x * 128, blockIdx.y * 128);
}

// ---------- fused dual attention (cross T=77 + id L=32), 1 thread = 1 query row ----------
// Q bf16 [B*S,1280]; Kp/Vp fp32 [384,1280] rows=(b*77+t); IKp/IVp fp32 [128,1280] rows=(b*32+t)
// writes combined bf16 [B*S,1280] at col h*64+d
// launch_bounds(256,2): VGPR budget 256/wave so q[64]+accC[64]+accI[64] stay in
// arch VGPRs (round-0: cap=112 forced AGPR shuffling, VALUBusy 26%). LDS 55.8KB
// limits to 2 blocks/CU = 8 waves = 2/EU, consistent.
__global__ __launch_bounds__(256, 2) void attn_kernel(
        const unsigned short* __restrict__ Q,
        const float* __restrict__ Kp, const float* __restrict__ Vp,
        const float* __restrict__ IKp, const float* __restrict__ IVp,
        unsigned short* __restrict__ Cmb) {
    const int b = blockIdx.z;
    const int h = blockIdx.y;
    const int s = blockIdx.x * 256 + threadIdx.x;
    const int hoff = h * 64;

    __shared__ float Kl[77 * 64];
    __shared__ float Vl[77 * 64];
    __shared__ float IKl[32 * 64];
    __shared__ float IVl[32 * 64];

    for (int i = threadIdx.x; i < 77 * 16; i += 256) {
        const int t = i >> 4, c4 = i & 15;
        const size_t src = (size_t)(b * 77 + t) * 1280 + hoff + c4 * 4;
        ((float4*)Kl)[i] = *(const float4*)(Kp + src);
        ((float4*)Vl)[i] = *(const float4*)(Vp + src);
    }
    for (int i = threadIdx.x; i < 32 * 16; i += 256) {
        const int t = i >> 4, c4 = i & 15;
        const size_t src = (size_t)(b * 32 + t) * 1280 + hoff + c4 * 4;
        ((float4*)IKl)[i] = *(const float4*)(IKp + src);
        ((float4*)IVl)[i] = *(const float4*)(IVp + src);
    }
    __syncthreads();

    // load q row (bf16 -> fp32)
    float q[64];
    const unsigned short* qp = Q + (size_t)(b * 4096 + s) * 1280 + hoff;
    #pragma unroll
    for (int c = 0; c < 8; ++c) {
        short8 v = *(const short8*)(qp + c * 8);
        #pragma unroll
        for (int j = 0; j < 8; ++j) q[c * 8 + j] = bf2f((unsigned short)v[j]);
    }

    const float scale = 0.125f;   // 1/sqrt(64)

    float accC[64];
    #pragma unroll
    for (int d = 0; d < 64; ++d) accC[d] = 0.f;
    float lC = 0.f;
    #pragma unroll 1
    for (int j = 0; j < 77; ++j) {
        const float* kr = Kl + j * 64;
        float s0 = 0.f, s1 = 0.f, s2 = 0.f, s3 = 0.f;
        #pragma unroll
        for (int d = 0; d < 64; d += 4) {
            s0 += q[d + 0] * kr[d + 0];
            s1 += q[d + 1] * kr[d + 1];
            s2 += q[d + 2] * kr[d + 2];
            s3 += q[d + 3] * kr[d + 3];
        }
        const float p = __expf(((s0 + s1) + (s2 + s3)) * scale);
        lC += p;
        const float* vr = Vl + j * 64;
        #pragma unroll
        for (int d = 0; d < 64; ++d) accC[d] += p * vr[d];
    }

    float accI[64];
    #pragma unroll
    for (int d = 0; d < 64; ++d) accI[d] = 0.f;
    float lI = 0.f;
    #pragma unroll 1
    for (int j = 0; j < 32; ++j) {
        const float* kr = IKl + j * 64;
        float s0 = 0.f, s1 = 0.f, s2 = 0.f, s3 = 0.f;
        #pragma unroll
        for (int d = 0; d < 64; d += 4) {
            s0 += q[d + 0] * kr[d + 0];
            s1 += q[d + 1] * kr[d + 1];
            s2 += q[d + 2] * kr[d + 2];
            s3 += q[d + 3] * kr[d + 3];
        }
        const float p = __expf(((s0 + s1) + (s2 + s3)) * scale);
        lI += p;
        const float* vr = IVl + j * 64;
        #pragma unroll
        for (int d = 0; d < 64; ++d) accI[d] += p * vr[d];
    }

    const float rC = 1.f / lC;
    const float rI = 1.f / lI;

    unsigned short* op = Cmb + (size_t)(b * 4096 + s) * 1280 + hoff;
    #pragma unroll
    for (int c = 0; c < 8; ++c) {
        ushort8 u;
        #pragma unroll
        for (int j = 0; j < 8; ++j) {
            const int d = c * 8 + j;
            u[j] = f2bf(accC[d] * rC + accI[d] * rI);
        }
        *(ushort8*)(op + c * 8) = u;
    }
}

// ---------- host launch ----------
extern "C" void kernel_launch(void* const* d_in, const int* in_sizes, int n_in,
                              void* d_out, int out_size, void* d_ws, size_t ws_size,
                              hipStream_t stream) {
    const float* hs  = (const float*)d_in[0];   // [4,4096,1280]
    const float* enc = (const float*)d_in[1];   // [4,77,2048]
    const float* idm = (const float*)d_in[2];   // [4,32,2048]
    const float* Wq  = (const float*)d_in[3];   // [1280,1280]
    const float* Wk  = (const float*)d_in[4];   // [1280,2048]
    const float* Wv  = (const float*)d_in[5];
    const float* Wik = (const float*)d_in[6];
    const float* Wiv = (const float*)d_in[7];
    const float* Wo  = (const float*)d_in[8];   // [1280,1280]
    const float* bo  = (const float*)d_in[9];   // [1280]
    float* out = (float*)d_out;

    char* ws = (char*)d_ws;
    size_t off = 0;
    auto carve = [&](size_t bytes) {
        char* p = ws + off;
        off += (bytes + 255) & ~(size_t)255;
        return p;
    };

    unsigned short* Xh   = (unsigned short*)carve(16384ULL * 1280 * 2); // also 'combined'
    unsigned short* Wq_b = (unsigned short*)carve(1280ULL * 1280 * 2);
    unsigned short* Wk_b = (unsigned short*)carve(1280ULL * 2048 * 2);
    unsigned short* Wv_b = (unsigned short*)carve(1280ULL * 2048 * 2);
    unsigned short* Wik_b= (unsigned short*)carve(1280ULL * 2048 * 2);
    unsigned short* Wiv_b= (unsigned short*)carve(1280ULL * 2048 * 2);
    unsigned short* Wo_b = (unsigned short*)carve(1280ULL * 1280 * 2);
    unsigned short* Encb = (unsigned short*)carve(308ULL * 2048 * 2);
    unsigned short* Idb  = (unsigned short*)carve(128ULL * 2048 * 2);
    unsigned short* Qb   = (unsigned short*)carve(16384ULL * 1280 * 2);
    float* Kp  = (float*)carve(384ULL * 1280 * 4);
    float* Vp  = (float*)carve(384ULL * 1280 * 4);
    float* IKp = (float*)carve(128ULL * 1280 * 4);
    float* IVp = (float*)carve(128ULL * 1280 * 4);
    (void)ws_size; (void)in_sizes; (void)n_in; (void)out_size;

    // big cast (hidden_states)
    cast_bf16_kernel<<<(4 * 4096 * 1280 / 4 + 255) / 256, 256, 0, stream>>>(
        hs, Xh, 4 * 4096 * 1280);

    // batched small casts (8 tensors, one launch)
    CastBatch cb;
    cb.src[0] = Wq;  cb.dst[0] = Wq_b;  cb.n[0] = 1280 * 1280;
    cb.src[1] = Wk;  cb.dst[1] = Wk_b;  cb.n[1] = 1280 * 2048;
    cb.src[2] = Wv;  cb.dst[2] = Wv_b;  cb.n[2] = 1280 * 2048;
    cb.src[3] = Wik; cb.dst[3] = Wik_b; cb.n[3] = 1280 * 2048;
    cb.src[4] = Wiv; cb.dst[4] = Wiv_b; cb.n[4] = 1280 * 2048;
    cb.src[5] = Wo;  cb.dst[5] = Wo_b;  cb.n[5] = 1280 * 1280;
    cb.src[6] = enc; cb.dst[6] = Encb;  cb.n[6] = 4 * 77 * 2048;
    cb.src[7] = idm; cb.dst[7] = Idb;   cb.n[7] = 4 * 32 * 2048;
    cast_batch_kernel<<<dim3((1280 * 2048 / 4 + 255) / 256, 8), 256, 0, stream>>>(cb);

    // Q = hs @ Wq^T   -> bf16 [16384,1280]
    gemm_bt_kernel<1><<<dim3(128, 10), 256, 0, stream>>>(
        Xh, Wq_b, nullptr, Qb, nullptr, nullptr, 16384, 1280, 1280);
    // K/V projections -> fp32 (padded to 384 rows), fused pairs via grid.z
    gemm_kv_kernel<<<dim3(3, 10, 2), 256, 0, stream>>>(
        Encb, Wk_b, Wv_b, Kp, Vp, 308, 1280, 2048);
    gemm_kv_kernel<<<dim3(1, 10, 2), 256, 0, stream>>>(
        Idb, Wik_b, Wiv_b, IKp, IVp, 128, 1280, 2048);

    // fused cross+id attention -> combined (reuses Xh buffer)
    attn_kernel<<<dim3(16, 20, 4), 256, 0, stream>>>(Qb, Kp, Vp, IKp, IVp, Xh);

    // out = combined @ Wo^T + bo + residual(hs)   -> fp32 d_out
    gemm_bt_kernel<2><<<dim3(128, 10), 256, 0, stream>>>(
        Xh, Wo_b, out, nullptr, bo, hs, 16384, 1280, 1280);
}